// Round 9
// baseline (283.751 us; speedup 1.0000x reference)
//
#include <hip/hip_runtime.h>

#define S_LEN 2048
#define D_MODEL 1024
#define NH 16
#define DH 64

typedef __attribute__((ext_vector_type(8))) short bf16x8;   // 8 bf16 = 4 VGPR
typedef __attribute__((ext_vector_type(4))) float f32x4;

__device__ __forceinline__ f32x4 mfma16(bf16x8 a, bf16x8 b, f32x4 c) {
  return __builtin_amdgcn_mfma_f32_16x16x32_bf16(a, b, c, 0, 0, 0);
}

__device__ __forceinline__ void ldst16(const ushort* g, ushort* l) {
  __builtin_amdgcn_global_load_lds(
      (const __attribute__((address_space(1))) void*)g,
      (__attribute__((address_space(3))) void*)l, 16, 0, 0);
}

__device__ __forceinline__ ushort bf16_rne(float f) {
  unsigned u = __float_as_uint(f);
  unsigned r = (u + 0x7FFFu + ((u >> 16) & 1u)) >> 16;
  return (ushort)r;
}
__device__ __forceinline__ float bf16_to_f(ushort u) {
  return __uint_as_float((unsigned)u << 16);
}

// ---------------------------------------------------------------------------
__global__ __launch_bounds__(256) void cast_bf16(
    const float* __restrict__ in, ushort* __restrict__ hi, int n4)
{
  int i = blockIdx.x * 256 + threadIdx.x;
  if (i >= n4) return;
  float4 v = ((const float4*)in)[i];
  ushort4 h;
  h.x = bf16_rne(v.x); h.y = bf16_rne(v.y);
  h.z = bf16_rne(v.z); h.w = bf16_rne(v.w);
  ((ushort4*)hi)[i] = h;
}

// ---------------------------------------------------------------------------
__global__ __launch_bounds__(256) void splitT(
    const float* __restrict__ W0, const float* __restrict__ W1,
    const float* __restrict__ W2, const float* __restrict__ W3,
    ushort* __restrict__ H0, ushort* __restrict__ L0,
    ushort* __restrict__ H1, ushort* __restrict__ L1,
    ushort* __restrict__ H2, ushort* __restrict__ L2,
    ushort* __restrict__ H3, ushort* __restrict__ L3)
{
  const int zz = blockIdx.z;
  const float* W = zz == 0 ? W0 : (zz == 1 ? W1 : (zz == 2 ? W2 : W3));
  ushort* H = zz == 0 ? H0 : (zz == 1 ? H1 : (zz == 2 ? H2 : H3));
  ushort* L = zz == 0 ? L0 : (zz == 1 ? L1 : (zz == 2 ? L2 : L3));
  __shared__ float ts[32][33];
  const int k0 = blockIdx.x * 32, n0 = blockIdx.y * 32;
  const int r = threadIdx.x >> 3, c4 = (threadIdx.x & 7) * 4;
  float4 v = *(const float4*)&W[(size_t)(k0 + r) * D_MODEL + n0 + c4];
  ts[r][c4 + 0] = v.x; ts[r][c4 + 1] = v.y; ts[r][c4 + 2] = v.z; ts[r][c4 + 3] = v.w;
  __syncthreads();
  ushort4 h, l;
#pragma unroll
  for (int ii = 0; ii < 4; ii++) {
    float f = ts[c4 + ii][r];
    ushort hb = bf16_rne(f);
    ushort lb = bf16_rne(f - __uint_as_float((unsigned)hb << 16));
    ((ushort*)&h)[ii] = hb;
    ((ushort*)&l)[ii] = lb;
  }
  *(ushort4*)&H[(size_t)(n0 + r) * D_MODEL + k0 + c4] = h;
  *(ushort4*)&L[(size_t)(n0 + r) * D_MODEL + k0 + c4] = l;
}

// ---------------------------------------------------------------------------
// bf16 2-term split GEMM (C = Ah*(Bh+Bl), fp32 acc), 64 x TN tile, BK=32.
// ---------------------------------------------------------------------------
template<int TN>
__global__ __launch_bounds__(256, 3) void gemm_t(
    const ushort* __restrict__ Ah,
    const ushort* __restrict__ B0h, const ushort* __restrict__ B0l,
    const ushort* __restrict__ B1h, const ushort* __restrict__ B1l,
    const ushort* __restrict__ B2h, const ushort* __restrict__ B2l,
    float* __restrict__ C0, int K, int mode,
    ushort* __restrict__ aqb, ushort* __restrict__ akb,
    ushort* __restrict__ akbT, ushort* __restrict__ avbT)
{
  const int t = threadIdx.x;
  const int w = t >> 6, lane = t & 63;
  const int quad = lane >> 4, lr = lane & 15;
  const int bx = blockIdx.x;
  const int bw = (bx * TN) >> 10;
  const int n0 = (bx * TN) & 1023;
  const int m0 = blockIdx.y * 64;
  const ushort* Bh = bw == 0 ? B0h : (bw == 1 ? B1h : B2h);
  const ushort* Bl = bw == 0 ? B0l : (bw == 1 ? B1l : B2l);

  __shared__ ushort sAh[64 * 32], sBh[TN * 32], sBl[TN * 32];

  constexpr int NF = TN / 32;   // n frags per wave
  f32x4 acc[2][NF];
#pragma unroll
  for (int mi = 0; mi < 2; mi++)
#pragma unroll
    for (int ni = 0; ni < NF; ni++)
#pragma unroll
      for (int r = 0; r < 4; r++) acc[mi][ni][r] = 0.f;

  const int mbase = (w & 1) * 32;
  const int nbase = (w >> 1) * (TN / 2);
  const int rowA = w * 16 + (lane >> 2), kcA = (lane & 3) * 8;

  for (int k0 = 0; k0 < K; k0 += 32) {
    __syncthreads();
    ldst16(Ah + (size_t)(m0 + rowA) * K + k0 + kcA, &sAh[w * 512]);
#pragma unroll
    for (int i = 0; i < TN / 64; i++) {
      int rowB = w * (TN / 4) + i * 16 + (lane >> 2);
      int base = (w * (TN / 4) + i * 16) * 32;
      ldst16(Bh + (size_t)(n0 + rowB) * K + k0 + kcA, &sBh[base]);
      ldst16(Bl + (size_t)(n0 + rowB) * K + k0 + kcA, &sBl[base]);
    }
    __syncthreads();

    bf16x8 ah[2], bh[NF], bl[NF];
#pragma unroll
    for (int mi = 0; mi < 2; mi++)
      ah[mi] = *(const bf16x8*)&sAh[(mbase + mi * 16 + lr) * 32 + quad * 8];
#pragma unroll
    for (int ni = 0; ni < NF; ni++) {
      int rown = nbase + ni * 16 + lr;
      bh[ni] = *(const bf16x8*)&sBh[rown * 32 + quad * 8];
      bl[ni] = *(const bf16x8*)&sBl[rown * 32 + quad * 8];
    }
#pragma unroll
    for (int mi = 0; mi < 2; mi++)
#pragma unroll
      for (int ni = 0; ni < NF; ni++) {
        acc[mi][ni] = mfma16(ah[mi], bh[ni], acc[mi][ni]);
        acc[mi][ni] = mfma16(ah[mi], bl[ni], acc[mi][ni]);
      }
  }

  if (mode == 0) {
#pragma unroll
    for (int mi = 0; mi < 2; mi++)
#pragma unroll
      for (int ni = 0; ni < NF; ni++)
#pragma unroll
        for (int r = 0; r < 4; r++) {
          int row = m0 + mbase + mi * 16 + quad * 4 + r;
          int col = n0 + nbase + ni * 16 + lr;
          C0[(size_t)row * 1024 + col] = acc[mi][ni][r];
        }
  } else if (bw == 0) {          // qb: bf16 row-major, pre-scaled 1/sqrt(d)
#pragma unroll
    for (int mi = 0; mi < 2; mi++)
#pragma unroll
      for (int ni = 0; ni < NF; ni++)
#pragma unroll
        for (int r = 0; r < 4; r++) {
          int row = m0 + mbase + mi * 16 + quad * 4 + r;
          int col = n0 + nbase + ni * 16 + lr;
          aqb[(size_t)row * 1024 + col] = bf16_rne(acc[mi][ni][r] * 0.125f);
        }
  } else if (bw == 1) {          // kb row-major + kbT [1024][2048]
#pragma unroll
    for (int mi = 0; mi < 2; mi++)
#pragma unroll
      for (int ni = 0; ni < NF; ni++) {
        int row0 = m0 + mbase + mi * 16 + quad * 4;
        int col = n0 + nbase + ni * 16 + lr;
        ushort4 pk;
#pragma unroll
        for (int r = 0; r < 4; r++) {
          ushort b = bf16_rne(acc[mi][ni][r]);
          ((ushort*)&pk)[r] = b;
          akb[(size_t)(row0 + r) * 1024 + col] = b;
        }
        *(ushort4*)&akbT[(size_t)col * 2048 + row0] = pk;
      }
  } else {                        // vbT [1024][2048]
#pragma unroll
    for (int mi = 0; mi < 2; mi++)
#pragma unroll
      for (int ni = 0; ni < NF; ni++) {
        int row0 = m0 + mbase + mi * 16 + quad * 4;
        int col = n0 + nbase + ni * 16 + lr;
        ushort4 pk;
#pragma unroll
        for (int r = 0; r < 4; r++)
          ((ushort*)&pk)[r] = bf16_rne(acc[mi][ni][r]);
        *(ushort4*)&avbT[(size_t)col * 2048 + row0] = pk;
      }
  }
}

// ---------------------------------------------------------------------------
// Fused, 256 threads: blocks 0..15 = memory update; 16..527 = attention.
// Attention K-loop is BARRIER-FREE: K A-frags and V B-frags are direct 16B
// contiguous global loads (kb row-major / vbT), Q B-frags live in registers,
// and P is wave-private in LDS (each wave writes+reads only its own 16-row
// strip; same-wave LDS ordering needs only lgkmcnt, no barrier).  Compiler
// can software-pipeline K/V loads across exp/MFMA — no vmcnt(0) drains.
// Swapped QK operands: D[m=j][n=q] -> P^T packs as ushort4 writes.
// ---------------------------------------------------------------------------
__global__ __launch_bounds__(256, 4) void attn_fused(
    const ushort* __restrict__ qb, const ushort* __restrict__ kb,
    const ushort* __restrict__ vbT, const ushort* __restrict__ kbT,
    const float* __restrict__ Mmem, const float* __restrict__ zmem,
    const float* __restrict__ beta,
    ushort* __restrict__ oh,
    float* __restrict__ Mout, float* __restrict__ zout)
{
  const int t = threadIdx.x;
  const int w = t >> 6, lane = t & 63;
  const int quad = lane >> 4, lr = lane & 15;

  __shared__ __align__(16) ushort sBuf[17408];  // 34.8 KB union
  __shared__ float drow[64];
  __shared__ float sL[64];

  if (blockIdx.x < 16) {
    // ================= memory update: M_out = M + sigma(K)^T V ==============
    const int h = blockIdx.x;
    float* red = (float*)sBuf;          // 2 x 4096 floats = 32 KB
    f32x4 acc[4][4];
#pragma unroll
    for (int mt = 0; mt < 4; mt++)
#pragma unroll
      for (int nt = 0; nt < 4; nt++)
#pragma unroll
        for (int r = 0; r < 4; r++) acc[mt][nt][r] = 0.f;
    float accZ[4] = {0.f, 0.f, 0.f, 0.f};

#pragma unroll 2
    for (int step = 0; step < 16; step++) {
      int k0 = w * 512 + step * 32;
      bf16x8 ah[4], al[4];
#pragma unroll
      for (int mt = 0; mt < 4; mt++) {
        bf16x8 raw = *(const bf16x8*)&kbT[(size_t)(h * 64 + mt * 16 + lr) * 2048 + k0 + quad * 8];
        bf16x8 hh, ll;
#pragma unroll
        for (int j = 0; j < 8; j++) {
          float f = bf16_to_f((ushort)raw[j]);
          float s = f > 0.f ? f + 1.f : __expf(f);
          accZ[mt] += s;
          ushort hb = bf16_rne(s);
          hh[j] = (short)hb;
          ll[j] = (short)bf16_rne(s - bf16_to_f(hb));
        }
        ah[mt] = hh; al[mt] = ll;
      }
      bf16x8 bv[4];
#pragma unroll
      for (int nt = 0; nt < 4; nt++)
        bv[nt] = *(const bf16x8*)&vbT[(size_t)(h * 64 + nt * 16 + lr) * 2048 + k0 + quad * 8];
#pragma unroll
      for (int mt = 0; mt < 4; mt++)
#pragma unroll
        for (int nt = 0; nt < 4; nt++) {
          acc[mt][nt] = mfma16(ah[mt], bv[nt], acc[mt][nt]);
          acc[mt][nt] = mfma16(al[mt], bv[nt], acc[mt][nt]);
        }
    }
#pragma unroll
    for (int mt = 0; mt < 4; mt++) {
      accZ[mt] += __shfl_xor(accZ[mt], 16);
      accZ[mt] += __shfl_xor(accZ[mt], 32);
    }
    if (w < 2) {
#pragma unroll
      for (int mt = 0; mt < 4; mt++)
#pragma unroll
        for (int nt = 0; nt < 4; nt++)
#pragma unroll
          for (int r = 0; r < 4; r++)
            red[w * 4096 + (mt * 16 + quad * 4 + r) * 64 + nt * 16 + lr] = acc[mt][nt][r];
    }
    __syncthreads();
    if (w >= 2) {
#pragma unroll
      for (int mt = 0; mt < 4; mt++)
#pragma unroll
        for (int nt = 0; nt < 4; nt++)
#pragma unroll
          for (int r = 0; r < 4; r++)
            red[(w - 2) * 4096 + (mt * 16 + quad * 4 + r) * 64 + nt * 16 + lr] += acc[mt][nt][r];
    }
    __syncthreads();
    for (int i = t; i < 4096; i += 256)
      Mout[(size_t)h * 4096 + i] = Mmem[(size_t)h * 4096 + i] + red[i] + red[4096 + i];
    __syncthreads();
    if (quad == 0) {
#pragma unroll
      for (int mt = 0; mt < 4; mt++)
        red[w * 64 + mt * 16 + lr] = accZ[mt];
    }
    __syncthreads();
    if (t < 64)
      zout[h * 64 + t] = zmem[h * 64 + t] + red[t] + red[64 + t] + red[128 + t] + red[192 + t];
    return;
  }

  // ====================== attention tile ====================================
  const int a  = blockIdx.x - 16;
  const int h  = a >> 5;
  const int p  = (a >> 1) & 15;
  const int qt = (a & 1) ? p : 31 - p;
  const int s0 = qt * 64;
  const int ntiles = (qt + 2) >> 1;

  const int arow = w * 16 + lr;     // this lane's q row within the 64-row tile
  // Q fragments straight from global into registers (16B contiguous)
  const bf16x8 aq0 = *(const bf16x8*)&qb[(size_t)(s0 + arow) * 1024 + h * 64 + quad * 8];
  const bf16x8 aq1 = *(const bf16x8*)&qb[(size_t)(s0 + arow) * 1024 + h * 64 + 32 + quad * 8];

  f32x4 oacc[4];
#pragma unroll
  for (int ni = 0; ni < 4; ni++)
#pragma unroll
    for (int r = 0; r < 4; r++) oacc[ni][r] = 0.f;
  f32x4 lacc;
#pragma unroll
  for (int r = 0; r < 4; r++) lacc[r] = 0.f;
  bf16x8 bone;
#pragma unroll
  for (int j = 0; j < 8; j++) bone[j] = (lr == 0) ? (short)0x3F80 : (short)0;

  const ushort* kbh  = kb  + h * 64;
  const ushort* vbh  = vbT + (size_t)(h * 64) * 2048;

  for (int jt = 0; jt < ntiles; jt++) {
    const int j0 = jt * 128;

    // ---- K^T Q (swapped): D[m=j][n=q]; K A-frags direct from global ----
    f32x4 sc[8];
#pragma unroll
    for (int nj = 0; nj < 8; nj++) {
      const ushort* kr = kbh + (size_t)(j0 + nj * 16 + lr) * 1024;
      bf16x8 k0 = *(const bf16x8*)&kr[quad * 8];
      bf16x8 k1 = *(const bf16x8*)&kr[32 + quad * 8];
      f32x4 z4; z4[0] = z4[1] = z4[2] = z4[3] = 0.f;
      z4 = mfma16(k0, aq0, z4);
      sc[nj] = mfma16(k1, aq1, z4);
    }
    if (jt == ntiles - 1) {                   // causal mask on final tile
#pragma unroll
      for (int nj = 0; nj < 8; nj++)
#pragma unroll
        for (int r = 0; r < 4; r++)
          if (j0 + nj * 16 + quad * 4 + r > s0 + arow) sc[nj][r] = -1e30f;
    }

    // ---- fixed-max softmax; packed ushort4 P^T writes (wave-private) ----
#pragma unroll
    for (int nj = 0; nj < 8; nj++) {
      ushort4 pk;
#pragma unroll
      for (int r = 0; r < 4; r++) {
        float e = exp2f(fmaf(sc[nj][r], 1.4426950408889634f, -23.083120654223414f));
        ((ushort*)&pk)[r] = bf16_rne(e);
      }
      int col = nj * 16 + quad * 4;
      *(ushort4*)&sBuf[arow * 128 + ((col + arow * 8) & 127)] = pk;
    }

    // ---- PV + row-sum l; V B-frags direct from global ----
#pragma unroll
    for (int kf = 0; kf < 4; kf++) {
      bf16x8 ap = *(const bf16x8*)&sBuf[arow * 128 + ((kf * 32 + quad * 8 + arow * 8) & 127)];
#pragma unroll
      for (int ni = 0; ni < 4; ni++) {
        bf16x8 bv = *(const bf16x8*)&vbh[(size_t)(ni * 16 + lr) * 2048 + j0 + kf * 32 + quad * 8];
        oacc[ni] = mfma16(ap, bv, oacc[ni]);
      }
      lacc = mfma16(ap, bone, lacc);
    }
  }
  __syncthreads();   // all waves done with P strips before epilogue overlay

  // ---- epilogue: A_mem + gate blend ----
  float* sF  = (float*)sBuf;
  float* sO  = sF;            // [64][68] unnormalized A_dot
  float* ssq = sF + 4352;     // [64 features][68]
  if (lr == 0) {
#pragma unroll
    for (int r = 0; r < 4; r++) sL[w * 16 + quad * 4 + r] = lacc[r];
  }
#pragma unroll
  for (int ni = 0; ni < 4; ni++)
#pragma unroll
    for (int r = 0; r < 4; r++)
      sO[(w * 16 + quad * 4 + r) * 68 + ni * 16 + lr] = oacc[ni][r];

#pragma unroll
  for (int i = 0; i < 4; i++) {
    int idx4 = t + i * 256;
    int r = idx4 >> 4, c4 = (idx4 & 15) * 4;
    ushort4 u4 = *(const ushort4*)&qb[(size_t)(s0 + r) * 1024 + h * 64 + c4];
#pragma unroll
    for (int j = 0; j < 4; j++) {
      float qv = bf16_to_f(((const ushort*)&u4)[j]) * 8.0f;   // undo 0.125
      ssq[(c4 + j) * 68 + r] = qv > 0.f ? qv + 1.f : __expf(qv);
    }
  }
  __syncthreads();

  {
    int rr2 = t >> 2, part = t & 3;
    float ds = 0.f;
#pragma unroll
    for (int jj = 0; jj < 16; jj++) {
      int c = part + jj * 4;
      ds = fmaf(ssq[c * 68 + rr2], zmem[h * 64 + c], ds);
    }
    ds += __shfl_xor(ds, 1);
    ds += __shfl_xor(ds, 2);
    if (part == 0) drow[rr2] = ds + 1e-6f;
  }
  __syncthreads();

  const int tx = t & 15, ty = t >> 4;
  float nacc[4][4] = {};
#pragma unroll 8
  for (int dd = 0; dd < 64; dd++) {
    float4 av = *(const float4*)&ssq[dd * 68 + ty * 4];
    float4 bv = *(const float4*)&Mmem[(size_t)h * 4096 + dd * 64 + tx * 4];
    float aa[4] = {av.x, av.y, av.z, av.w};
    float bb[4] = {bv.x, bv.y, bv.z, bv.w};
#pragma unroll
    for (int i = 0; i < 4; i++)
#pragma unroll
      for (int j = 0; j < 4; j++)
        nacc[i][j] = fmaf(aa[i], bb[j], nacc[i][j]);
  }
  float g = 1.f / (1.f + __expf(-beta[h]));
#pragma unroll
  for (int i = 0; i < 4; i++) {
    int r = ty * 4 + i;
    float invd = g / drow[r];
    float invl = (1.f - g) / sL[r];
    float4 od = *(const float4*)&sO[r * 68 + tx * 4];
    float b0 = nacc[i][0] * invd + od.x * invl;
    float b1 = nacc[i][1] * invd + od.y * invl;
    float b2 = nacc[i][2] * invd + od.z * invl;
    float b3 = nacc[i][3] * invd + od.w * invl;
    ushort4 hh;
    hh.x = bf16_rne(b0); hh.y = bf16_rne(b1);
    hh.z = bf16_rne(b2); hh.w = bf16_rne(b3);
    *(ushort4*)&oh[(size_t)(s0 + r) * 1024 + h * 64 + tx * 4] = hh;
  }
}

// ---------------------------------------------------------------------------
extern "C" void kernel_launch(void* const* d_in, const int* in_sizes, int n_in,
                              void* d_out, int out_size, void* d_ws, size_t ws_size,
                              hipStream_t stream) {
  const float* x    = (const float*)d_in[0];
  const float* M    = (const float*)d_in[1];
  const float* z    = (const float*)d_in[2];
  const float* Wq   = (const float*)d_in[3];
  const float* Wk   = (const float*)d_in[4];
  const float* Wv   = (const float*)d_in[5];
  const float* Wo   = (const float*)d_in[6];
  const float* beta = (const float*)d_in[7];

  float* out  = (float*)d_out;
  float* Mout = out + (size_t)S_LEN * D_MODEL;
  float* zout = Mout + NH*DH*DH;

  const size_t NE = (size_t)S_LEN * D_MODEL;   // 2M
  const size_t WE = (size_t)D_MODEL * D_MODEL; // 1M
  ushort* xh  = (ushort*)d_ws;
  ushort* wqh = xh + NE;
  ushort* wql = wqh + WE;
  ushort* wkh = wql + WE;
  ushort* wkl = wkh + WE;
  ushort* wvh = wkl + WE;
  ushort* wvl = wvh + WE;
  ushort* woh = wvl + WE;
  ushort* wol = woh + WE;
  ushort* qb  = wol + WE;
  ushort* kb  = qb + NE;
  ushort* kbT = kb + NE;
  ushort* vbT = kbT + NE;
  ushort* ohb = vbT + NE;

  cast_bf16<<<dim3(NE/4/256), 256, 0, stream>>>(x, xh, (int)(NE/4));
  splitT<<<dim3(32, 32, 4), 256, 0, stream>>>(Wq, Wk, Wv, Wo,
      wqh, wql, wkh, wkl, wvh, wvl, woh, wol);

  // fused qkv GEMM -> qb (scaled), kb, kbT, vbT
  gemm_t<128><<<dim3(24, 32), 256, 0, stream>>>(xh,
      wqh, wql, wkh, wkl, wvh, wvl,
      (float*)nullptr, D_MODEL, 1, qb, kb, kbT, vbT);

  // fused: memory update (blocks 0..15) + attention (blocks 16..527)
  attn_fused<<<dim3(528), 256, 0, stream>>>(qb, kb, vbT, kbT,
      M, z, beta, ohb, Mout, zout);

  // out projection (fp32 C, 2-term split)
  gemm_t<64><<<dim3(16, 32), 256, 0, stream>>>(ohb,
      woh, wol, woh, wol, woh, wol,
      out, D_MODEL, 0, nullptr, nullptr, nullptr, nullptr);
}

// Round 10
// 184.756 us; speedup vs baseline: 1.5358x; 1.5358x over previous
//
#include <hip/hip_runtime.h>

#define S_LEN 2048
#define D_MODEL 1024
#define NH 16
#define DH 64

typedef __attribute__((ext_vector_type(8))) short bf16x8;   // 8 bf16 = 4 VGPR
typedef __attribute__((ext_vector_type(4))) float f32x4;

__device__ __forceinline__ f32x4 mfma16(bf16x8 a, bf16x8 b, f32x4 c) {
  return __builtin_amdgcn_mfma_f32_16x16x32_bf16(a, b, c, 0, 0, 0);
}

__device__ __forceinline__ void ldst16(const ushort* g, ushort* l) {
  __builtin_amdgcn_global_load_lds(
      (const __attribute__((address_space(1))) void*)g,
      (__attribute__((address_space(3))) void*)l, 16, 0, 0);
}

__device__ __forceinline__ ushort bf16_rne(float f) {
  unsigned u = __float_as_uint(f);
  unsigned r = (u + 0x7FFFu + ((u >> 16) & 1u)) >> 16;
  return (ushort)r;
}
__device__ __forceinline__ float bf16_to_f(ushort u) {
  return __uint_as_float((unsigned)u << 16);
}

// ---------------------------------------------------------------------------
__global__ __launch_bounds__(256) void cast_bf16(
    const float* __restrict__ in, ushort* __restrict__ hi, int n4)
{
  int i = blockIdx.x * 256 + threadIdx.x;
  if (i >= n4) return;
  float4 v = ((const float4*)in)[i];
  ushort4 h;
  h.x = bf16_rne(v.x); h.y = bf16_rne(v.y);
  h.z = bf16_rne(v.z); h.w = bf16_rne(v.w);
  ((ushort4*)hi)[i] = h;
}

// ---------------------------------------------------------------------------
__global__ __launch_bounds__(256) void splitT(
    const float* __restrict__ W0, const float* __restrict__ W1,
    const float* __restrict__ W2, const float* __restrict__ W3,
    ushort* __restrict__ H0, ushort* __restrict__ L0,
    ushort* __restrict__ H1, ushort* __restrict__ L1,
    ushort* __restrict__ H2, ushort* __restrict__ L2,
    ushort* __restrict__ H3, ushort* __restrict__ L3)
{
  const int zz = blockIdx.z;
  const float* W = zz == 0 ? W0 : (zz == 1 ? W1 : (zz == 2 ? W2 : W3));
  ushort* H = zz == 0 ? H0 : (zz == 1 ? H1 : (zz == 2 ? H2 : H3));
  ushort* L = zz == 0 ? L0 : (zz == 1 ? L1 : (zz == 2 ? L2 : L3));
  __shared__ float ts[32][33];
  const int k0 = blockIdx.x * 32, n0 = blockIdx.y * 32;
  const int r = threadIdx.x >> 3, c4 = (threadIdx.x & 7) * 4;
  float4 v = *(const float4*)&W[(size_t)(k0 + r) * D_MODEL + n0 + c4];
  ts[r][c4 + 0] = v.x; ts[r][c4 + 1] = v.y; ts[r][c4 + 2] = v.z; ts[r][c4 + 3] = v.w;
  __syncthreads();
  ushort4 h, l;
#pragma unroll
  for (int ii = 0; ii < 4; ii++) {
    float f = ts[c4 + ii][r];
    ushort hb = bf16_rne(f);
    ushort lb = bf16_rne(f - __uint_as_float((unsigned)hb << 16));
    ((ushort*)&h)[ii] = hb;
    ((ushort*)&l)[ii] = lb;
  }
  *(ushort4*)&H[(size_t)(n0 + r) * D_MODEL + k0 + c4] = h;
  *(ushort4*)&L[(size_t)(n0 + r) * D_MODEL + k0 + c4] = l;
}

// ---------------------------------------------------------------------------
// bf16 MFMA GEMM, 64 x TN tile, BK=32.  TWO=1: C = Ah*(Bh+Bl) (2-term, for
// fp32 out-projection).  TWO=0: C = Ah*Bh single-term (qkv — results are
// stored bf16 anyway, so the Bl refinement is sub-ulp of the stored value).
// mode 0: fp32 C.  mode 1 (qkv): bw0 -> qb bf16(C*0.125); bw1 -> kb + kbT;
// bw2 -> vbT.
// ---------------------------------------------------------------------------
template<int TN, int TWO>
__global__ __launch_bounds__(256, 3) void gemm_t(
    const ushort* __restrict__ Ah,
    const ushort* __restrict__ B0h, const ushort* __restrict__ B0l,
    const ushort* __restrict__ B1h, const ushort* __restrict__ B1l,
    const ushort* __restrict__ B2h, const ushort* __restrict__ B2l,
    float* __restrict__ C0, int K, int mode,
    ushort* __restrict__ aqb, ushort* __restrict__ akb,
    ushort* __restrict__ akbT, ushort* __restrict__ avbT)
{
  const int t = threadIdx.x;
  const int w = t >> 6, lane = t & 63;
  const int quad = lane >> 4, lr = lane & 15;
  const int bx = blockIdx.x;
  const int bw = (bx * TN) >> 10;
  const int n0 = (bx * TN) & 1023;
  const int m0 = blockIdx.y * 64;
  const ushort* Bh = bw == 0 ? B0h : (bw == 1 ? B1h : B2h);
  const ushort* Bl = bw == 0 ? B0l : (bw == 1 ? B1l : B2l);

  __shared__ ushort sAh[64 * 32];
  __shared__ ushort sBh[TN * 32];
  __shared__ ushort sBl[(TWO ? TN : 1) * 32];

  constexpr int NF = TN / 32;   // n frags per wave
  f32x4 acc[2][NF];
#pragma unroll
  for (int mi = 0; mi < 2; mi++)
#pragma unroll
    for (int ni = 0; ni < NF; ni++)
#pragma unroll
      for (int r = 0; r < 4; r++) acc[mi][ni][r] = 0.f;

  const int mbase = (w & 1) * 32;
  const int nbase = (w >> 1) * (TN / 2);
  const int rowA = w * 16 + (lane >> 2), kcA = (lane & 3) * 8;

  for (int k0 = 0; k0 < K; k0 += 32) {
    __syncthreads();
    ldst16(Ah + (size_t)(m0 + rowA) * K + k0 + kcA, &sAh[w * 512]);
#pragma unroll
    for (int i = 0; i < TN / 64; i++) {
      int rowB = w * (TN / 4) + i * 16 + (lane >> 2);
      int base = (w * (TN / 4) + i * 16) * 32;
      ldst16(Bh + (size_t)(n0 + rowB) * K + k0 + kcA, &sBh[base]);
      if (TWO)
        ldst16(Bl + (size_t)(n0 + rowB) * K + k0 + kcA, &sBl[base]);
    }
    __syncthreads();

    bf16x8 ah[2], bh[NF], bl[NF];
#pragma unroll
    for (int mi = 0; mi < 2; mi++)
      ah[mi] = *(const bf16x8*)&sAh[(mbase + mi * 16 + lr) * 32 + quad * 8];
#pragma unroll
    for (int ni = 0; ni < NF; ni++) {
      int rown = nbase + ni * 16 + lr;
      bh[ni] = *(const bf16x8*)&sBh[rown * 32 + quad * 8];
      if (TWO) bl[ni] = *(const bf16x8*)&sBl[rown * 32 + quad * 8];
    }
#pragma unroll
    for (int mi = 0; mi < 2; mi++)
#pragma unroll
      for (int ni = 0; ni < NF; ni++) {
        acc[mi][ni] = mfma16(ah[mi], bh[ni], acc[mi][ni]);
        if (TWO) acc[mi][ni] = mfma16(ah[mi], bl[ni], acc[mi][ni]);
      }
  }

  if (mode == 0) {
#pragma unroll
    for (int mi = 0; mi < 2; mi++)
#pragma unroll
      for (int ni = 0; ni < NF; ni++)
#pragma unroll
        for (int r = 0; r < 4; r++) {
          int row = m0 + mbase + mi * 16 + quad * 4 + r;
          int col = n0 + nbase + ni * 16 + lr;
          C0[(size_t)row * 1024 + col] = acc[mi][ni][r];
        }
  } else if (bw == 0) {          // qb: bf16 row-major, pre-scaled 1/sqrt(d)
#pragma unroll
    for (int mi = 0; mi < 2; mi++)
#pragma unroll
      for (int ni = 0; ni < NF; ni++)
#pragma unroll
        for (int r = 0; r < 4; r++) {
          int row = m0 + mbase + mi * 16 + quad * 4 + r;
          int col = n0 + nbase + ni * 16 + lr;
          aqb[(size_t)row * 1024 + col] = bf16_rne(acc[mi][ni][r] * 0.125f);
        }
  } else if (bw == 1) {          // kb row-major + kbT [1024][2048]
#pragma unroll
    for (int mi = 0; mi < 2; mi++)
#pragma unroll
      for (int ni = 0; ni < NF; ni++) {
        int row0 = m0 + mbase + mi * 16 + quad * 4;
        int col = n0 + nbase + ni * 16 + lr;
        ushort4 pk;
#pragma unroll
        for (int r = 0; r < 4; r++) {
          ushort b = bf16_rne(acc[mi][ni][r]);
          ((ushort*)&pk)[r] = b;
          akb[(size_t)(row0 + r) * 1024 + col] = b;
        }
        *(ushort4*)&akbT[(size_t)col * 2048 + row0] = pk;
      }
  } else {                        // vbT [1024][2048]
#pragma unroll
    for (int mi = 0; mi < 2; mi++)
#pragma unroll
      for (int ni = 0; ni < NF; ni++) {
        int row0 = m0 + mbase + mi * 16 + quad * 4;
        int col = n0 + nbase + ni * 16 + lr;
        ushort4 pk;
#pragma unroll
        for (int r = 0; r < 4; r++)
          ((ushort*)&pk)[r] = bf16_rne(acc[mi][ni][r]);
        *(ushort4*)&avbT[(size_t)col * 2048 + row0] = pk;
      }
  }
}

// ---------------------------------------------------------------------------
// Fused, 256 threads (round-7 structure — measured 58 µs): blocks 0..15 =
// memory update; 16..527 = attention tiles in equal-work pair order.
// Fixed-max softmax (no cross-lane reductions); row-sum l via ones-column
// MFMA; Q in registers; P overlays the Q LDS region; 128-key j-tiles staged
// via global_load_lds (2 barriers/iter).
// ---------------------------------------------------------------------------
__global__ __launch_bounds__(256, 3) void attn_fused(
    const ushort* __restrict__ qb, const ushort* __restrict__ kb,
    const ushort* __restrict__ vbT, const ushort* __restrict__ kbT,
    const float* __restrict__ Mmem, const float* __restrict__ zmem,
    const float* __restrict__ beta,
    ushort* __restrict__ oh,
    float* __restrict__ Mout, float* __restrict__ zout)
{
  const int t = threadIdx.x;
  const int w = t >> 6, lane = t & 63;
  const int quad = lane >> 4, lr = lane & 15;

  __shared__ __align__(16) ushort sBuf[24576];  // 48 KB union
  __shared__ float drow[64];
  __shared__ float sL[64];

  if (blockIdx.x < 16) {
    // ================= memory update: M_out = M + sigma(K)^T V ==============
    const int h = blockIdx.x;
    float* red = (float*)sBuf;          // 2 x 4096 floats = 32 KB
    f32x4 acc[4][4];
#pragma unroll
    for (int mt = 0; mt < 4; mt++)
#pragma unroll
      for (int nt = 0; nt < 4; nt++)
#pragma unroll
        for (int r = 0; r < 4; r++) acc[mt][nt][r] = 0.f;
    float accZ[4] = {0.f, 0.f, 0.f, 0.f};

#pragma unroll 2
    for (int step = 0; step < 16; step++) {
      int k0 = w * 512 + step * 32;
      bf16x8 ah[4], al[4];
#pragma unroll
      for (int mt = 0; mt < 4; mt++) {
        bf16x8 raw = *(const bf16x8*)&kbT[(size_t)(h * 64 + mt * 16 + lr) * 2048 + k0 + quad * 8];
        bf16x8 hh, ll;
#pragma unroll
        for (int j = 0; j < 8; j++) {
          float f = bf16_to_f((ushort)raw[j]);
          float s = f > 0.f ? f + 1.f : __expf(f);
          accZ[mt] += s;
          ushort hb = bf16_rne(s);
          hh[j] = (short)hb;
          ll[j] = (short)bf16_rne(s - bf16_to_f(hb));
        }
        ah[mt] = hh; al[mt] = ll;
      }
      bf16x8 bv[4];
#pragma unroll
      for (int nt = 0; nt < 4; nt++)
        bv[nt] = *(const bf16x8*)&vbT[(size_t)(h * 64 + nt * 16 + lr) * 2048 + k0 + quad * 8];
#pragma unroll
      for (int mt = 0; mt < 4; mt++)
#pragma unroll
        for (int nt = 0; nt < 4; nt++) {
          acc[mt][nt] = mfma16(ah[mt], bv[nt], acc[mt][nt]);
          acc[mt][nt] = mfma16(al[mt], bv[nt], acc[mt][nt]);
        }
    }
#pragma unroll
    for (int mt = 0; mt < 4; mt++) {
      accZ[mt] += __shfl_xor(accZ[mt], 16);
      accZ[mt] += __shfl_xor(accZ[mt], 32);
    }
    if (w < 2) {
#pragma unroll
      for (int mt = 0; mt < 4; mt++)
#pragma unroll
        for (int nt = 0; nt < 4; nt++)
#pragma unroll
          for (int r = 0; r < 4; r++)
            red[w * 4096 + (mt * 16 + quad * 4 + r) * 64 + nt * 16 + lr] = acc[mt][nt][r];
    }
    __syncthreads();
    if (w >= 2) {
#pragma unroll
      for (int mt = 0; mt < 4; mt++)
#pragma unroll
        for (int nt = 0; nt < 4; nt++)
#pragma unroll
          for (int r = 0; r < 4; r++)
            red[(w - 2) * 4096 + (mt * 16 + quad * 4 + r) * 64 + nt * 16 + lr] += acc[mt][nt][r];
    }
    __syncthreads();
    for (int i = t; i < 4096; i += 256)
      Mout[(size_t)h * 4096 + i] = Mmem[(size_t)h * 4096 + i] + red[i] + red[4096 + i];
    __syncthreads();
    if (quad == 0) {
#pragma unroll
      for (int mt = 0; mt < 4; mt++)
        red[w * 64 + mt * 16 + lr] = accZ[mt];
    }
    __syncthreads();
    if (t < 64)
      zout[h * 64 + t] = zmem[h * 64 + t] + red[t] + red[64 + t] + red[128 + t] + red[192 + t];
    return;
  }

  // ====================== attention tile ====================================
  const int a  = blockIdx.x - 16;
  const int h  = a >> 5;
  const int p  = (a >> 1) & 15;
  const int qt = (a & 1) ? p : 31 - p;
  const int s0 = qt * 64;
  const int ntiles = (qt + 2) >> 1;

  const int SPQ = 0, SK = 8192, SVT = 16384;   // ushort offsets

  // stage Q (rotate-by-row layout) and pull into registers
#pragma unroll
  for (int i = 0; i < 2; i++) {
    int li = w * 2 + i;                       // 0..7
    int row = li * 8 + (lane >> 3);
    int cg = ((lane & 7) - row) & 7;
    ldst16(qb + (size_t)(s0 + row) * 1024 + h * 64 + cg * 8, &sBuf[SPQ + li * 512]);
  }
  __syncthreads();
  const int arow = w * 16 + lr;
  const bf16x8 aq0 = *(const bf16x8*)&sBuf[SPQ + arow * 64 + ((quad + arow) & 7) * 8];
  const bf16x8 aq1 = *(const bf16x8*)&sBuf[SPQ + arow * 64 + ((4 + quad + arow) & 7) * 8];

  f32x4 oacc[4];
#pragma unroll
  for (int ni = 0; ni < 4; ni++)
#pragma unroll
    for (int r = 0; r < 4; r++) oacc[ni][r] = 0.f;
  f32x4 lacc;
#pragma unroll
  for (int r = 0; r < 4; r++) lacc[r] = 0.f;
  bf16x8 bone;
#pragma unroll
  for (int j = 0; j < 8; j++) bone[j] = (lr == 0) ? (short)0x3F80 : (short)0;

  for (int jt = 0; jt < ntiles; jt++) {
    const int j0 = jt * 128;
    __syncthreads();                          // prev-iter LDS reads done
#pragma unroll
    for (int i = 0; i < 4; i++) {
      int li = w * 4 + i;                     // 0..15
      int rowK = li * 8 + (lane >> 3);        // 0..127
      int cgK = ((lane & 7) - rowK) & 7;
      ldst16(kb + (size_t)(j0 + rowK) * 1024 + h * 64 + cgK * 8,
             &sBuf[SK + li * 512]);
      int rowV = li * 4 + (lane >> 4);        // 0..63
      int cgV = ((lane & 15) - rowV) & 15;
      ldst16(vbT + (size_t)(h * 64 + rowV) * 2048 + j0 + cgV * 8,
             &sBuf[SVT + li * 512]);
    }
    __syncthreads();                          // staging landed

    // ---- QK^T: 64 rows x 128 cols ----
    f32x4 sc[8];
#pragma unroll
    for (int nj = 0; nj < 8; nj++) {
      int brow = nj * 16 + lr;
      bf16x8 b0 = *(const bf16x8*)&sBuf[SK + brow * 64 + ((quad + brow) & 7) * 8];
      bf16x8 b1 = *(const bf16x8*)&sBuf[SK + brow * 64 + ((4 + quad + brow) & 7) * 8];
      f32x4 z4; z4[0] = z4[1] = z4[2] = z4[3] = 0.f;
      z4 = mfma16(aq0, b0, z4);
      sc[nj] = mfma16(aq1, b1, z4);
    }
    if (jt == ntiles - 1) {                   // causal mask on final tile
#pragma unroll
      for (int nj = 0; nj < 8; nj++)
#pragma unroll
        for (int r = 0; r < 4; r++)
          if (j0 + nj * 16 + lr > s0 + w * 16 + quad * 4 + r) sc[nj][r] = -1e30f;
    }

    // ---- fixed-max softmax: P = exp2(s*log2e - 16*log2e); write bf16 P ----
#pragma unroll
    for (int nj = 0; nj < 8; nj++)
#pragma unroll
      for (int r = 0; r < 4; r++) {
        float e = exp2f(fmaf(sc[nj][r], 1.4426950408889634f, -23.083120654223414f));
        int rr2 = w * 16 + quad * 4 + r;
        sBuf[SPQ + rr2 * 128 + ((nj * 16 + lr + rr2 * 8) & 127)] = bf16_rne(e);
      }

    // ---- PV + row-sum l (wave-private P strip; no barrier needed) ----
    bf16x8 ap[4];
#pragma unroll
    for (int kf = 0; kf < 4; kf++)
      ap[kf] = *(const bf16x8*)&sBuf[SPQ + arow * 128 + ((kf * 32 + quad * 8 + arow * 8) & 127)];
#pragma unroll
    for (int ni = 0; ni < 4; ni++) {
      int brow = ni * 16 + lr;
#pragma unroll
      for (int kf = 0; kf < 4; kf++) {
        bf16x8 bv = *(const bf16x8*)&sBuf[SVT + brow * 128 + ((kf * 32 + quad * 8 + brow * 8) & 127)];
        oacc[ni] = mfma16(ap[kf], bv, oacc[ni]);
      }
    }
#pragma unroll
    for (int kf = 0; kf < 4; kf++)
      lacc = mfma16(ap[kf], bone, lacc);
  }
  __syncthreads();   // all waves done with P/V LDS before epilogue overlay

  // ---- epilogue: A_mem + gate blend ----
  float* sF  = (float*)sBuf;
  float* sO  = sF;            // [64][68] unnormalized A_dot
  float* ssq = sF + 4352;     // [64 features][68]
  if (lr == 0) {
#pragma unroll
    for (int r = 0; r < 4; r++) sL[w * 16 + quad * 4 + r] = lacc[r];
  }
#pragma unroll
  for (int ni = 0; ni < 4; ni++)
#pragma unroll
    for (int r = 0; r < 4; r++)
      sO[(w * 16 + quad * 4 + r) * 68 + ni * 16 + lr] = oacc[ni][r];

#pragma unroll
  for (int i = 0; i < 4; i++) {
    int idx4 = t + i * 256;
    int r = idx4 >> 4, c4 = (idx4 & 15) * 4;
    ushort4 u4 = *(const ushort4*)&qb[(size_t)(s0 + r) * 1024 + h * 64 + c4];
#pragma unroll
    for (int j = 0; j < 4; j++) {
      float qv = bf16_to_f(((const ushort*)&u4)[j]) * 8.0f;   // undo 0.125
      ssq[(c4 + j) * 68 + r] = qv > 0.f ? qv + 1.f : __expf(qv);
    }
  }
  __syncthreads();

  {
    int rr2 = t >> 2, part = t & 3;
    float ds = 0.f;
#pragma unroll
    for (int jj = 0; jj < 16; jj++) {
      int c = part + jj * 4;
      ds = fmaf(ssq[c * 68 + rr2], zmem[h * 64 + c], ds);
    }
    ds += __shfl_xor(ds, 1);
    ds += __shfl_xor(ds, 2);
    if (part == 0) drow[rr2] = ds + 1e-6f;
  }
  __syncthreads();

  const int tx = t & 15, ty = t >> 4;
  float nacc[4][4] = {};
#pragma unroll 8
  for (int dd = 0; dd < 64; dd++) {
    float4 av = *(const float4*)&ssq[dd * 68 + ty * 4];
    float4 bv = *(const float4*)&Mmem[(size_t)h * 4096 + dd * 64 + tx * 4];
    float aa[4] = {av.x, av.y, av.z, av.w};
    float bb[4] = {bv.x, bv.y, bv.z, bv.w};
#pragma unroll
    for (int i = 0; i < 4; i++)
#pragma unroll
      for (int j = 0; j < 4; j++)
        nacc[i][j] = fmaf(aa[i], bb[j], nacc[i][j]);
  }
  float g = 1.f / (1.f + __expf(-beta[h]));
#pragma unroll
  for (int i = 0; i < 4; i++) {
    int r = ty * 4 + i;
    float invd = g / drow[r];
    float invl = (1.f - g) / sL[r];
    float4 od = *(const float4*)&sO[r * 68 + tx * 4];
    float b0 = nacc[i][0] * invd + od.x * invl;
    float b1 = nacc[i][1] * invd + od.y * invl;
    float b2 = nacc[i][2] * invd + od.z * invl;
    float b3 = nacc[i][3] * invd + od.w * invl;
    ushort4 hh;
    hh.x = bf16_rne(b0); hh.y = bf16_rne(b1);
    hh.z = bf16_rne(b2); hh.w = bf16_rne(b3);
    *(ushort4*)&oh[(size_t)(s0 + r) * 1024 + h * 64 + tx * 4] = hh;
  }
}

// ---------------------------------------------------------------------------
extern "C" void kernel_launch(void* const* d_in, const int* in_sizes, int n_in,
                              void* d_out, int out_size, void* d_ws, size_t ws_size,
                              hipStream_t stream) {
  const float* x    = (const float*)d_in[0];
  const float* M    = (const float*)d_in[1];
  const float* z    = (const float*)d_in[2];
  const float* Wq   = (const float*)d_in[3];
  const float* Wk   = (const float*)d_in[4];
  const float* Wv   = (const float*)d_in[5];
  const float* Wo   = (const float*)d_in[6];
  const float* beta = (const float*)d_in[7];

  float* out  = (float*)d_out;
  float* Mout = out + (size_t)S_LEN * D_MODEL;
  float* zout = Mout + NH*DH*DH;

  const size_t NE = (size_t)S_LEN * D_MODEL;   // 2M
  const size_t WE = (size_t)D_MODEL * D_MODEL; // 1M
  ushort* xh  = (ushort*)d_ws;
  ushort* wqh = xh + NE;
  ushort* wql = wqh + WE;
  ushort* wkh = wql + WE;
  ushort* wkl = wkh + WE;
  ushort* wvh = wkl + WE;
  ushort* wvl = wvh + WE;
  ushort* woh = wvl + WE;
  ushort* wol = woh + WE;
  ushort* qb  = wol + WE;
  ushort* kb  = qb + NE;
  ushort* kbT = kb + NE;
  ushort* vbT = kbT + NE;
  ushort* ohb = vbT + NE;

  cast_bf16<<<dim3(NE/4/256), 256, 0, stream>>>(x, xh, (int)(NE/4));
  splitT<<<dim3(32, 32, 4), 256, 0, stream>>>(Wq, Wk, Wv, Wo,
      wqh, wql, wkh, wkl, wvh, wvl, woh, wol);

  // fused qkv GEMM (single-term bf16) -> qb (scaled), kb, kbT, vbT
  gemm_t<128, 0><<<dim3(24, 32), 256, 0, stream>>>(xh,
      wqh, wql, wkh, wkl, wvh, wvl,
      (float*)nullptr, D_MODEL, 1, qb, kb, kbT, vbT);

  // fused: memory update (blocks 0..15) + attention (blocks 16..527)
  attn_fused<<<dim3(528), 256, 0, stream>>>(qb, kb, vbT, kbT,
      M, z, beta, ohb, Mout, zout);

  // out projection (fp32 C, 2-term split)
  gemm_t<64, 1><<<dim3(16, 32), 256, 0, stream>>>(ohb,
      woh, wol, woh, wol, woh, wol,
      out, D_MODEL, 0, nullptr, nullptr, nullptr, nullptr);
}

// Round 11
// 182.259 us; speedup vs baseline: 1.5569x; 1.0137x over previous
//
#include <hip/hip_runtime.h>

#define S_LEN 2048
#define D_MODEL 1024
#define NH 16
#define DH 64

typedef __attribute__((ext_vector_type(8))) short bf16x8;   // 8 bf16 = 4 VGPR
typedef __attribute__((ext_vector_type(4))) float f32x4;

__device__ __forceinline__ f32x4 mfma16(bf16x8 a, bf16x8 b, f32x4 c) {
  return __builtin_amdgcn_mfma_f32_16x16x32_bf16(a, b, c, 0, 0, 0);
}

__device__ __forceinline__ void ldst16(const ushort* g, ushort* l) {
  __builtin_amdgcn_global_load_lds(
      (const __attribute__((address_space(1))) void*)g,
      (__attribute__((address_space(3))) void*)l, 16, 0, 0);
}

__device__ __forceinline__ ushort bf16_rne(float f) {
  unsigned u = __float_as_uint(f);
  unsigned r = (u + 0x7FFFu + ((u >> 16) & 1u)) >> 16;
  return (ushort)r;
}
__device__ __forceinline__ float bf16_to_f(ushort u) {
  return __uint_as_float((unsigned)u << 16);
}

// ---------------------------------------------------------------------------
__global__ __launch_bounds__(256) void cast_bf16(
    const float* __restrict__ in, ushort* __restrict__ hi, int n4)
{
  int i = blockIdx.x * 256 + threadIdx.x;
  if (i >= n4) return;
  float4 v = ((const float4*)in)[i];
  ushort4 h;
  h.x = bf16_rne(v.x); h.y = bf16_rne(v.y);
  h.z = bf16_rne(v.z); h.w = bf16_rne(v.w);
  ((ushort4*)hi)[i] = h;
}

// ---------------------------------------------------------------------------
// transpose + cast 1024x1024 fp32 W -> WhT [n][k] bf16 (hi only); z picks W.
// ---------------------------------------------------------------------------
__global__ __launch_bounds__(256) void castT(
    const float* __restrict__ W0, const float* __restrict__ W1,
    const float* __restrict__ W2, const float* __restrict__ W3,
    ushort* __restrict__ H0, ushort* __restrict__ H1,
    ushort* __restrict__ H2, ushort* __restrict__ H3)
{
  const int zz = blockIdx.z;
  const float* W = zz == 0 ? W0 : (zz == 1 ? W1 : (zz == 2 ? W2 : W3));
  ushort* H = zz == 0 ? H0 : (zz == 1 ? H1 : (zz == 2 ? H2 : H3));
  __shared__ float ts[32][33];
  const int k0 = blockIdx.x * 32, n0 = blockIdx.y * 32;
  const int r = threadIdx.x >> 3, c4 = (threadIdx.x & 7) * 4;
  float4 v = *(const float4*)&W[(size_t)(k0 + r) * D_MODEL + n0 + c4];
  ts[r][c4 + 0] = v.x; ts[r][c4 + 1] = v.y; ts[r][c4 + 2] = v.z; ts[r][c4 + 3] = v.w;
  __syncthreads();
  ushort4 h;
#pragma unroll
  for (int ii = 0; ii < 4; ii++)
    ((ushort*)&h)[ii] = bf16_rne(ts[c4 + ii][r]);
  *(ushort4*)&H[(size_t)(n0 + r) * D_MODEL + k0 + c4] = h;
}

// ---------------------------------------------------------------------------
// bf16 single-term MFMA GEMM (C = Ah*Bh, fp32 acc), TM x TN tile, BK=32,
// 4 waves as 2x2 of (TM/2)x(TN/2).  mode 0: fp32 C.  mode 1 (qkv):
// bw0 -> qb bf16(C*0.125); bw1 -> kb + kbT; bw2 -> vbT.
// ---------------------------------------------------------------------------
template<int TM, int TN>
__global__ __launch_bounds__(256, 3) void gemm_h(
    const ushort* __restrict__ Ah,
    const ushort* __restrict__ B0h, const ushort* __restrict__ B1h,
    const ushort* __restrict__ B2h,
    float* __restrict__ C0, int K, int mode,
    ushort* __restrict__ aqb, ushort* __restrict__ akb,
    ushort* __restrict__ akbT, ushort* __restrict__ avbT)
{
  const int t = threadIdx.x;
  const int w = t >> 6, lane = t & 63;
  const int quad = lane >> 4, lr = lane & 15;
  const int bx = blockIdx.x;
  const int bw = (bx * TN) >> 10;
  const int n0 = (bx * TN) & 1023;
  const int m0 = blockIdx.y * TM;
  const ushort* Bh = bw == 0 ? B0h : (bw == 1 ? B1h : B2h);

  __shared__ ushort sAh[TM * 32], sBh[TN * 32];

  constexpr int MF = TM / 32, NF = TN / 32;   // frags per wave
  f32x4 acc[MF][NF];
#pragma unroll
  for (int mi = 0; mi < MF; mi++)
#pragma unroll
    for (int ni = 0; ni < NF; ni++)
#pragma unroll
      for (int r = 0; r < 4; r++) acc[mi][ni][r] = 0.f;

  const int mbase = (w & 1) * (TM / 2);
  const int nbase = (w >> 1) * (TN / 2);
  const int rsub = lane >> 2, kcA = (lane & 3) * 8;

  for (int k0 = 0; k0 < K; k0 += 32) {
    __syncthreads();
#pragma unroll
    for (int i = 0; i < TM / 64; i++) {
      int row = i * 64 + w * 16 + rsub;
      ldst16(Ah + (size_t)(m0 + row) * K + k0 + kcA, &sAh[(i * 64 + w * 16) * 32]);
    }
#pragma unroll
    for (int i = 0; i < TN / 64; i++) {
      int row = i * 64 + w * 16 + rsub;
      ldst16(Bh + (size_t)(n0 + row) * K + k0 + kcA, &sBh[(i * 64 + w * 16) * 32]);
    }
    __syncthreads();

    bf16x8 ah[MF], bh[NF];
#pragma unroll
    for (int mi = 0; mi < MF; mi++)
      ah[mi] = *(const bf16x8*)&sAh[(mbase + mi * 16 + lr) * 32 + quad * 8];
#pragma unroll
    for (int ni = 0; ni < NF; ni++)
      bh[ni] = *(const bf16x8*)&sBh[(nbase + ni * 16 + lr) * 32 + quad * 8];
#pragma unroll
    for (int mi = 0; mi < MF; mi++)
#pragma unroll
      for (int ni = 0; ni < NF; ni++)
        acc[mi][ni] = mfma16(ah[mi], bh[ni], acc[mi][ni]);
  }

  if (mode == 0) {
#pragma unroll
    for (int mi = 0; mi < MF; mi++)
#pragma unroll
      for (int ni = 0; ni < NF; ni++)
#pragma unroll
        for (int r = 0; r < 4; r++) {
          int row = m0 + mbase + mi * 16 + quad * 4 + r;
          int col = n0 + nbase + ni * 16 + lr;
          C0[(size_t)row * 1024 + col] = acc[mi][ni][r];
        }
  } else if (bw == 0) {          // qb: bf16 row-major, pre-scaled 1/sqrt(d)
#pragma unroll
    for (int mi = 0; mi < MF; mi++)
#pragma unroll
      for (int ni = 0; ni < NF; ni++)
#pragma unroll
        for (int r = 0; r < 4; r++) {
          int row = m0 + mbase + mi * 16 + quad * 4 + r;
          int col = n0 + nbase + ni * 16 + lr;
          aqb[(size_t)row * 1024 + col] = bf16_rne(acc[mi][ni][r] * 0.125f);
        }
  } else if (bw == 1) {          // kb row-major + kbT [1024][2048]
#pragma unroll
    for (int mi = 0; mi < MF; mi++)
#pragma unroll
      for (int ni = 0; ni < NF; ni++) {
        int row0 = m0 + mbase + mi * 16 + quad * 4;
        int col = n0 + nbase + ni * 16 + lr;
        ushort4 pk;
#pragma unroll
        for (int r = 0; r < 4; r++) {
          ushort b = bf16_rne(acc[mi][ni][r]);
          ((ushort*)&pk)[r] = b;
          akb[(size_t)(row0 + r) * 1024 + col] = b;
        }
        *(ushort4*)&akbT[(size_t)col * 2048 + row0] = pk;
      }
  } else {                        // vbT [1024][2048]
#pragma unroll
    for (int mi = 0; mi < MF; mi++)
#pragma unroll
      for (int ni = 0; ni < NF; ni++) {
        int row0 = m0 + mbase + mi * 16 + quad * 4;
        int col = n0 + nbase + ni * 16 + lr;
        ushort4 pk;
#pragma unroll
        for (int r = 0; r < 4; r++)
          ((ushort*)&pk)[r] = bf16_rne(acc[mi][ni][r]);
        *(ushort4*)&avbT[(size_t)col * 2048 + row0] = pk;
      }
  }
}

// ---------------------------------------------------------------------------
// Fused, 256 threads: blocks 0..15 = memory update; 16..527 = attention tiles
// (equal-work pair order).  Round-7 2-barrier staging structure, but BOTH
// attention MFMAs use swapped operands:
//   scores: A=K, B=Q  -> lane holds 4 consecutive j for one q -> P row-chunks
//           pack into ushort4 ds_write_b64 (8 writes vs 32 scalar).
//   PV:     A=V^T, B=P -> O^T in regs -> lane holds 4 consecutive d -> float4
//           sO writes.  Row-sum l via all-ones A fragment.
// Fragment READS are bit-identical to the round-7 kernel (verified layouts).
// ---------------------------------------------------------------------------
__global__ __launch_bounds__(256, 3) void attn_fused(
    const ushort* __restrict__ qb, const ushort* __restrict__ kb,
    const ushort* __restrict__ vbT, const ushort* __restrict__ kbT,
    const float* __restrict__ Mmem, const float* __restrict__ zmem,
    const float* __restrict__ beta,
    ushort* __restrict__ oh,
    float* __restrict__ Mout, float* __restrict__ zout)
{
  const int t = threadIdx.x;
  const int w = t >> 6, lane = t & 63;
  const int quad = lane >> 4, lr = lane & 15;

  __shared__ __align__(16) ushort sBuf[24576];  // 48 KB union
  __shared__ float drow[64];
  __shared__ float sL[64];

  if (blockIdx.x < 16) {
    // ================= memory update: M_out = M + sigma(K)^T V ==============
    const int h = blockIdx.x;
    float* red = (float*)sBuf;          // 2 x 4096 floats = 32 KB
    f32x4 acc[4][4];
#pragma unroll
    for (int mt = 0; mt < 4; mt++)
#pragma unroll
      for (int nt = 0; nt < 4; nt++)
#pragma unroll
        for (int r = 0; r < 4; r++) acc[mt][nt][r] = 0.f;
    float accZ[4] = {0.f, 0.f, 0.f, 0.f};

#pragma unroll 2
    for (int step = 0; step < 16; step++) {
      int k0 = w * 512 + step * 32;
      bf16x8 ah[4], al[4];
#pragma unroll
      for (int mt = 0; mt < 4; mt++) {
        bf16x8 raw = *(const bf16x8*)&kbT[(size_t)(h * 64 + mt * 16 + lr) * 2048 + k0 + quad * 8];
        bf16x8 hh, ll;
#pragma unroll
        for (int j = 0; j < 8; j++) {
          float f = bf16_to_f((ushort)raw[j]);
          float s = f > 0.f ? f + 1.f : __expf(f);
          accZ[mt] += s;
          ushort hb = bf16_rne(s);
          hh[j] = (short)hb;
          ll[j] = (short)bf16_rne(s - bf16_to_f(hb));
        }
        ah[mt] = hh; al[mt] = ll;
      }
      bf16x8 bv[4];
#pragma unroll
      for (int nt = 0; nt < 4; nt++)
        bv[nt] = *(const bf16x8*)&vbT[(size_t)(h * 64 + nt * 16 + lr) * 2048 + k0 + quad * 8];
#pragma unroll
      for (int mt = 0; mt < 4; mt++)
#pragma unroll
        for (int nt = 0; nt < 4; nt++) {
          acc[mt][nt] = mfma16(ah[mt], bv[nt], acc[mt][nt]);
          acc[mt][nt] = mfma16(al[mt], bv[nt], acc[mt][nt]);
        }
    }
#pragma unroll
    for (int mt = 0; mt < 4; mt++) {
      accZ[mt] += __shfl_xor(accZ[mt], 16);
      accZ[mt] += __shfl_xor(accZ[mt], 32);
    }
    if (w < 2) {
#pragma unroll
      for (int mt = 0; mt < 4; mt++)
#pragma unroll
        for (int nt = 0; nt < 4; nt++)
#pragma unroll
          for (int r = 0; r < 4; r++)
            red[w * 4096 + (mt * 16 + quad * 4 + r) * 64 + nt * 16 + lr] = acc[mt][nt][r];
    }
    __syncthreads();
    if (w >= 2) {
#pragma unroll
      for (int mt = 0; mt < 4; mt++)
#pragma unroll
        for (int nt = 0; nt < 4; nt++)
#pragma unroll
          for (int r = 0; r < 4; r++)
            red[(w - 2) * 4096 + (mt * 16 + quad * 4 + r) * 64 + nt * 16 + lr] += acc[mt][nt][r];
    }
    __syncthreads();
    for (int i = t; i < 4096; i += 256)
      Mout[(size_t)h * 4096 + i] = Mmem[(size_t)h * 4096 + i] + red[i] + red[4096 + i];
    __syncthreads();
    if (quad == 0) {
#pragma unroll
      for (int mt = 0; mt < 4; mt++)
        red[w * 64 + mt * 16 + lr] = accZ[mt];
    }
    __syncthreads();
    if (t < 64)
      zout[h * 64 + t] = zmem[h * 64 + t] + red[t] + red[64 + t] + red[128 + t] + red[192 + t];
    return;
  }

  // ====================== attention tile ====================================
  const int a  = blockIdx.x - 16;
  const int h  = a >> 5;
  const int p  = (a >> 1) & 15;
  const int qt = (a & 1) ? p : 31 - p;
  const int s0 = qt * 64;
  const int ntiles = (qt + 2) >> 1;

  const int SPQ = 0, SK = 8192, SVT = 16384;   // ushort offsets

  // stage Q (rotate-by-row layout) and pull into registers
#pragma unroll
  for (int i = 0; i < 2; i++) {
    int li = w * 2 + i;                       // 0..7
    int row = li * 8 + (lane >> 3);
    int cg = ((lane & 7) - row) & 7;
    ldst16(qb + (size_t)(s0 + row) * 1024 + h * 64 + cg * 8, &sBuf[SPQ + li * 512]);
  }
  __syncthreads();
  const int arow = w * 16 + lr;               // this lane's q row
  const bf16x8 aq0 = *(const bf16x8*)&sBuf[SPQ + arow * 64 + ((quad + arow) & 7) * 8];
  const bf16x8 aq1 = *(const bf16x8*)&sBuf[SPQ + arow * 64 + ((4 + quad + arow) & 7) * 8];

  f32x4 oaccT[4];                             // O^T: d = ni*16+quad*4+r, q = arow
#pragma unroll
  for (int ni = 0; ni < 4; ni++)
#pragma unroll
    for (int r = 0; r < 4; r++) oaccT[ni][r] = 0.f;
  f32x4 lacc;
#pragma unroll
  for (int r = 0; r < 4; r++) lacc[r] = 0.f;
  bf16x8 aone;
#pragma unroll
  for (int j = 0; j < 8; j++) aone[j] = (short)0x3F80;   // all ones

  for (int jt = 0; jt < ntiles; jt++) {
    const int j0 = jt * 128;
    __syncthreads();                          // prev-iter LDS reads done
#pragma unroll
    for (int i = 0; i < 4; i++) {
      int li = w * 4 + i;                     // 0..15
      int rowK = li * 8 + (lane >> 3);        // 0..127
      int cgK = ((lane & 7) - rowK) & 7;
      ldst16(kb + (size_t)(j0 + rowK) * 1024 + h * 64 + cgK * 8,
             &sBuf[SK + li * 512]);
      int rowV = li * 4 + (lane >> 4);        // 0..63
      int cgV = ((lane & 15) - rowV) & 15;
      ldst16(vbT + (size_t)(h * 64 + rowV) * 2048 + j0 + cgV * 8,
             &sBuf[SVT + li * 512]);
    }
    __syncthreads();                          // staging landed

    // ---- scores (swapped): A=K, B=Q -> sc[nj][r] = S[j=j0+nj*16+quad*4+r][q=arow]
    f32x4 sc[8];
#pragma unroll
    for (int nj = 0; nj < 8; nj++) {
      int brow = nj * 16 + lr;
      bf16x8 b0 = *(const bf16x8*)&sBuf[SK + brow * 64 + ((quad + brow) & 7) * 8];
      bf16x8 b1 = *(const bf16x8*)&sBuf[SK + brow * 64 + ((4 + quad + brow) & 7) * 8];
      f32x4 z4; z4[0] = z4[1] = z4[2] = z4[3] = 0.f;
      z4 = mfma16(b0, aq0, z4);
      sc[nj] = mfma16(b1, aq1, z4);
    }
    if (jt == ntiles - 1) {                   // causal: mask j > q
#pragma unroll
      for (int nj = 0; nj < 8; nj++)
#pragma unroll
        for (int r = 0; r < 4; r++)
          if (j0 + nj * 16 + quad * 4 + r > s0 + arow) sc[nj][r] = -1e30f;
    }

    // ---- fixed-max softmax; packed ushort4 P writes (wave-private rows) ----
#pragma unroll
    for (int nj = 0; nj < 8; nj++) {
      ushort4 pk;
#pragma unroll
      for (int r = 0; r < 4; r++) {
        float e = exp2f(fmaf(sc[nj][r], 1.4426950408889634f, -23.083120654223414f));
        ((ushort*)&pk)[r] = bf16_rne(e);
      }
      int col = nj * 16 + quad * 4;
      *(ushort4*)&sBuf[SPQ + arow * 128 + ((col + arow * 8) & 127)] = pk;
    }

    // ---- PV (swapped): A=V^T, B=P -> O^T; l via all-ones A ----
#pragma unroll
    for (int kf = 0; kf < 4; kf++) {
      bf16x8 bp = *(const bf16x8*)&sBuf[SPQ + arow * 128 + ((kf * 32 + quad * 8 + arow * 8) & 127)];
#pragma unroll
      for (int ni = 0; ni < 4; ni++) {
        int vrow = ni * 16 + lr;
        bf16x8 av = *(const bf16x8*)&sBuf[SVT + vrow * 128 + ((kf * 32 + quad * 8 + vrow * 8) & 127)];
        oaccT[ni] = mfma16(av, bp, oaccT[ni]);
      }
      lacc = mfma16(aone, bp, lacc);
    }
  }
  __syncthreads();   // all waves done with P/V LDS before epilogue overlay

  // ---- epilogue: A_mem + gate blend ----
  float* sF  = (float*)sBuf;
  float* sO  = sF;            // [64][68] unnormalized A_dot
  float* ssq = sF + 4352;     // [64 features][68]
  if (quad == 0) sL[arow] = lacc[0];          // l_q replicated over rows
#pragma unroll
  for (int ni = 0; ni < 4; ni++) {            // float4: 4 consecutive d
    float4 o4 = make_float4(oaccT[ni][0], oaccT[ni][1], oaccT[ni][2], oaccT[ni][3]);
    *(float4*)&sO[arow * 68 + ni * 16 + quad * 4] = o4;
  }

#pragma unroll
  for (int i = 0; i < 4; i++) {
    int idx4 = t + i * 256;
    int r = idx4 >> 4, c4 = (idx4 & 15) * 4;
    ushort4 u4 = *(const ushort4*)&qb[(size_t)(s0 + r) * 1024 + h * 64 + c4];
#pragma unroll
    for (int j = 0; j < 4; j++) {
      float qv = bf16_to_f(((const ushort*)&u4)[j]) * 8.0f;   // undo 0.125
      ssq[(c4 + j) * 68 + r] = qv > 0.f ? qv + 1.f : __expf(qv);
    }
  }
  __syncthreads();

  {
    int rr2 = t >> 2, part = t & 3;
    float ds = 0.f;
#pragma unroll
    for (int jj = 0; jj < 16; jj++) {
      int c = part + jj * 4;
      ds = fmaf(ssq[c * 68 + rr2], zmem[h * 64 + c], ds);
    }
    ds += __shfl_xor(ds, 1);
    ds += __shfl_xor(ds, 2);
    if (part == 0) drow[rr2] = ds + 1e-6f;
  }
  __syncthreads();

  const int tx = t & 15, ty = t >> 4;
  float nacc[4][4] = {};
#pragma unroll 8
  for (int dd = 0; dd < 64; dd++) {
    float4 av = *(const float4*)&ssq[dd * 68 + ty * 4];
    float4 bv = *(const float4*)&Mmem[(size_t)h * 4096 + dd * 64 + tx * 4];
    float aa[4] = {av.x, av.y, av.z, av.w};
    float bb[4] = {bv.x, bv.y, bv.z, bv.w};
#pragma unroll
    for (int i = 0; i < 4; i++)
#pragma unroll
      for (int j = 0; j < 4; j++)
        nacc[i][j] = fmaf(aa[i], bb[j], nacc[i][j]);
  }
  float g = 1.f / (1.f + __expf(-beta[h]));
#pragma unroll
  for (int i = 0; i < 4; i++) {
    int r = ty * 4 + i;
    float invd = g / drow[r];
    float invl = (1.f - g) / sL[r];
    float4 od = *(const float4*)&sO[r * 68 + tx * 4];
    float b0 = nacc[i][0] * invd + od.x * invl;
    float b1 = nacc[i][1] * invd + od.y * invl;
    float b2 = nacc[i][2] * invd + od.z * invl;
    float b3 = nacc[i][3] * invd + od.w * invl;
    ushort4 hh;
    hh.x = bf16_rne(b0); hh.y = bf16_rne(b1);
    hh.z = bf16_rne(b2); hh.w = bf16_rne(b3);
    *(ushort4*)&oh[(size_t)(s0 + r) * 1024 + h * 64 + tx * 4] = hh;
  }
}

// ---------------------------------------------------------------------------
extern "C" void kernel_launch(void* const* d_in, const int* in_sizes, int n_in,
                              void* d_out, int out_size, void* d_ws, size_t ws_size,
                              hipStream_t stream) {
  const float* x    = (const float*)d_in[0];
  const float* M    = (const float*)d_in[1];
  const float* z    = (const float*)d_in[2];
  const float* Wq   = (const float*)d_in[3];
  const float* Wk   = (const float*)d_in[4];
  const float* Wv   = (const float*)d_in[5];
  const float* Wo   = (const float*)d_in[6];
  const float* beta = (const float*)d_in[7];

  float* out  = (float*)d_out;
  float* Mout = out + (size_t)S_LEN * D_MODEL;
  float* zout = Mout + NH*DH*DH;

  const size_t NE = (size_t)S_LEN * D_MODEL;   // 2M
  const size_t WE = (size_t)D_MODEL * D_MODEL; // 1M
  ushort* xh  = (ushort*)d_ws;
  ushort* wqh = xh + NE;
  ushort* wkh = wqh + WE;
  ushort* wvh = wkh + WE;
  ushort* woh = wvh + WE;
  ushort* qb  = woh + WE;
  ushort* kb  = qb + NE;
  ushort* kbT = kb + NE;
  ushort* vbT = kbT + NE;
  ushort* ohb = vbT + NE;

  cast_bf16<<<dim3(NE/4/256), 256, 0, stream>>>(x, xh, (int)(NE/4));
  castT<<<dim3(32, 32, 4), 256, 0, stream>>>(Wq, Wk, Wv, Wo,
      wqh, wkh, wvh, woh);

  // fused qkv GEMM (128x128 single-term) -> qb (scaled), kb, kbT, vbT
  gemm_h<128, 128><<<dim3(24, 16), 256, 0, stream>>>(xh,
      wqh, wkh, wvh,
      (float*)nullptr, D_MODEL, 1, qb, kb, kbT, vbT);

  // fused: memory update (blocks 0..15) + attention (blocks 16..527)
  attn_fused<<<dim3(528), 256, 0, stream>>>(qb, kb, vbT, kbT,
      M, z, beta, ohb, Mout, zout);

  // out projection (fp32 C, single-term, 64x128 tile)
  gemm_h<64, 128><<<dim3(8, 32), 256, 0, stream>>>(ohb,
      woh, woh, woh,
      out, D_MODEL, 0, nullptr, nullptr, nullptr, nullptr);
}